// Round 14
// baseline (254.764 us; speedup 1.0000x reference)
//
#include <hip/hip_runtime.h>
#include <stdint.h>

// B=8, S=1024, H=1024, NH=16, HD=64
typedef __attribute__((ext_vector_type(8))) __bf16 bf16x8;
typedef __attribute__((ext_vector_type(8))) unsigned short ushortx8;
typedef __attribute__((ext_vector_type(4))) unsigned short ushortx4;
typedef __attribute__((ext_vector_type(4))) short short4v;
typedef __attribute__((ext_vector_type(4))) float floatx4;

#define LOG2E 1.4426950408889634f
#define QSCALE 0.18033688011112043f   // 0.125 * log2e

#define ASYNC16(g, l) __builtin_amdgcn_global_load_lds( \
    (__attribute__((address_space(1))) void*)(g),       \
    (__attribute__((address_space(3))) void*)(l), 16, 0, 0)

__device__ __forceinline__ unsigned short f2bf(float f) {
    unsigned int u = __float_as_uint(f);
    u += 0x7fffu + ((u >> 16) & 1u);   // round-to-nearest-even
    return (unsigned short)(u >> 16);
}
__device__ __forceinline__ float bf2f(unsigned short u) {
    return __uint_as_float((unsigned)u << 16);
}

// raw v_exp_f32 (2^x). libm exp2f without -ffast-math lowers to a guarded
// __ocml sequence (~6-10 VALU insts); the raw instruction is 1. Inputs here are
// bounded softmax logits; sub-2^-126 results flush to 0 = correct underflow.
__device__ __forceinline__ float fast_exp2(float x) {
#if __has_builtin(__builtin_amdgcn_exp2f)
    return __builtin_amdgcn_exp2f(x);
#else
    float r;
    asm("v_exp_f32 %0, %1" : "=v"(r) : "v"(x));
    return r;
#endif
}

__device__ __forceinline__ floatx4 mfma32(bf16x8 a, bf16x8 b, floatx4 c) {
    return __builtin_amdgcn_mfma_f32_16x16x32_bf16(a, b, c, 0, 0, 0);
}
__device__ __forceinline__ floatx4 mfma16(short4v a, short4v b, floatx4 c) {
    return __builtin_amdgcn_mfma_f32_16x16x16bf16_1k(a, b, c, 0, 0, 0);
}

// ---------------- fp32 -> bf16 converts (hidden + all 4 weights, one launch) --------
__global__ __launch_bounds__(256) void cvt_all(
    const float* __restrict__ hidden,
    const float* __restrict__ Wq, const float* __restrict__ Wk,
    const float* __restrict__ Wv, const float* __restrict__ Wo,
    unsigned short* __restrict__ hid_bf,
    unsigned short* __restrict__ oqkv, unsigned short* __restrict__ oo)
{
    const float* src;
    unsigned short* dst;
    int i;
    if (blockIdx.x < 4096) {
        src = hidden; dst = hid_bf;
        i = blockIdx.x * 256 + threadIdx.x;          // < 1048576
    } else {
        int blk = (blockIdx.x - 4096) >> 9;
        src = (blk == 0) ? Wq : (blk == 1) ? Wk : (blk == 2) ? Wv : Wo;
        dst = (blk == 3) ? oo : oqkv + (size_t)blk * 1048576;
        i = ((blockIdx.x - 4096) & 511) * 256 + threadIdx.x;   // < 131072
    }
    const float4* p = (const float4*)src + (size_t)i * 2;
    float4 a = p[0], b = p[1];
    ushortx8 o;
    o[0] = f2bf(a.x); o[1] = f2bf(a.y); o[2] = f2bf(a.z); o[3] = f2bf(a.w);
    o[4] = f2bf(b.x); o[5] = f2bf(b.y); o[6] = f2bf(b.z); o[7] = f2bf(b.w);
    *((ushortx8*)dst + i) = o;
}

// ---------- 128x128-tile double-buffered K-loop, ONE barrier per K-tile -------------
// (used by gemm_proj; 64 KB LDS -> 2 blocks/CU)
template<bool SWAP>
__device__ __forceinline__ void kloop_dbuf(
    const unsigned short* __restrict__ Ag,   // pre-offset by srow*1024+scol
    const unsigned short* __restrict__ Wg,
    unsigned short As[2][8192], unsigned short Bs[2][8192],
    int wm, int wn, int l16, int quad, int t,
    floatx4 acc[4][4])
{
    const int t8 = t * 8;
#define SAx(bf_, i_, kt_) ASYNC16(Ag + (size_t)(i_) * 32 * 1024 + (kt_) * 64, &As[bf_][(i_) * 2048 + t8])
#define SBx(bf_, i_, kt_) ASYNC16(Wg + (size_t)(i_) * 32 * 1024 + (kt_) * 64, &Bs[bf_][(i_) * 2048 + t8])
#pragma unroll
    for (int i = 0; i < 4; i++) { SAx(0, i, 0); SBx(0, i, 0); }
    __syncthreads();

#pragma unroll 1
    for (int kt = 0; kt < 16; ++kt) {
        const int cur = kt & 1, nb = cur ^ 1;
        if (kt < 15) {
#pragma unroll
            for (int i = 0; i < 4; i++) { SAx(nb, i, kt + 1); SBx(nb, i, kt + 1); }
        }
#pragma unroll
        for (int s = 0; s < 2; s++) {
            int pb = ((s * 4 + quad) ^ (l16 & 7)) * 8;
            bf16x8 af[4], bfr[4];
#pragma unroll
            for (int mt = 0; mt < 4; mt++)
                af[mt] = *(const bf16x8*)(&As[cur][(wm + mt * 16 + l16) * 64 + pb]);
#pragma unroll
            for (int nt = 0; nt < 4; nt++)
                bfr[nt] = *(const bf16x8*)(&Bs[cur][(wn + nt * 16 + l16) * 64 + pb]);
            if (SWAP) {
#pragma unroll
                for (int ft = 0; ft < 4; ft++)
#pragma unroll
                    for (int st = 0; st < 4; st++)
                        acc[ft][st] = mfma32(bfr[ft], af[st], acc[ft][st]);
            } else {
#pragma unroll
                for (int mt = 0; mt < 4; mt++)
#pragma unroll
                    for (int nt = 0; nt < 4; nt++)
                        acc[mt][nt] = mfma32(af[mt], bfr[nt], acc[mt][nt]);
            }
        }
        __syncthreads();
    }
#undef SAx
#undef SBx
}

// ---------------- merged QKV GEMM: 128x384 via A-shared 3 N-reps, 64 KB LDS ---------
// grid (64, 8) = 512 blocks = one balanced round at 2 blocks/CU. Staged 512 MB.
__global__ __launch_bounds__(256, 2) void gemm_qkv(
    const unsigned short* __restrict__ A,   // [8192][1024] bf16
    const unsigned short* __restrict__ W,   // [Wq;Wk;Wv] [3072][1024]
    const float* __restrict__ bq, const float* __restrict__ bk, const float* __restrict__ bv,
    unsigned short* __restrict__ Qo, unsigned short* __restrict__ Ko,
    unsigned short* __restrict__ Vo)
{
    __shared__ unsigned short As[2][8192];   // [ktbuf][128*64]
    __shared__ unsigned short Bs[2][8192];   // [pingpong][128*64]
    const int t = threadIdx.x;
    const int wave = t >> 6, lane = t & 63;
    const int quad = lane >> 4, l16 = lane & 15;
    const int wm = (wave >> 1) * 64, wn = (wave & 1) * 64;
    const int srow = t >> 3;
    const int scol = ((t & 7) ^ (srow & 7)) * 8;
    const int t8 = t * 8;

    const unsigned short* Ab = A + ((size_t)blockIdx.x * 128 + srow) * 1024 + scol;
    const unsigned short* Wb = W + ((size_t)blockIdx.y * 384 + srow) * 1024 + scol;

#define SA(bf_, i_, kt_) ASYNC16(Ab + (size_t)(i_) * 32768 + (kt_) * 64, &As[bf_][(i_) * 2048 + t8])
#define SB(rb_, i_, rp_, kt_) ASYNC16(Wb + (size_t)(rp_) * 131072 + (size_t)(i_) * 32768 + (kt_) * 64, \
                                      &Bs[rb_][(i_) * 2048 + t8])
#define REPC(RP, BB)                                                                   \
    do {                                                                               \
        _Pragma("unroll")                                                              \
        for (int s = 0; s < 2; s++) {                                                  \
            int pb = ((s * 4 + quad) ^ (l16 & 7)) * 8;                                 \
            bf16x8 af[4], bfr[4];                                                      \
            _Pragma("unroll")                                                          \
            for (int mt = 0; mt < 4; mt++)                                             \
                af[mt] = *(const bf16x8*)(&As[cur][(wm + mt * 16 + l16) * 64 + pb]);   \
            _Pragma("unroll")                                                          \
            for (int ft = 0; ft < 4; ft++)                                             \
                bfr[ft] = *(const bf16x8*)(&Bs[BB][(wn + ft * 16 + l16) * 64 + pb]);   \
            _Pragma("unroll")                                                          \
            for (int ft = 0; ft < 4; ft++)                                             \
                _Pragma("unroll")                                                      \
                for (int st = 0; st < 4; st++)                                         \
                    acc[RP][ft][st] = mfma32(bfr[ft], af[st], acc[RP][ft][st]);        \
        }                                                                              \
    } while (0)

    // prologue: A(0) + rep0(0) -> Bs[0]
#pragma unroll
    for (int i = 0; i < 4; i++) { SA(0, i, 0); SB(0, i, 0, 0); }
    __syncthreads();

    floatx4 acc[3][4][4] = {};   // [rep][ft][st]

#pragma unroll 1
    for (int kt = 0; kt < 16; ++kt) {
        const int cur = kt & 1, nb = cur ^ 1;

        // ---- P0: stage rep1(kt)->Bs[nb]; compute rep0 (As[cur], Bs[cur]) ----
#pragma unroll
        for (int i = 0; i < 4; i++) SB(nb, i, 1, kt);
        REPC(0, cur);
        __syncthreads();

        // ---- P1: stage rep2(kt)->Bs[cur]; compute rep1 (As[cur], Bs[nb]) ----
#pragma unroll
        for (int i = 0; i < 4; i++) SB(cur, i, 2, kt);
        REPC(1, nb);
        __syncthreads();

        // ---- P2: stage rep0(kt+1)->Bs[nb] + A(kt+1)->As[nb]; compute rep2 ----
        if (kt < 15) {
#pragma unroll
            for (int i = 0; i < 4; i++) { SB(nb, i, 0, kt + 1); SA(nb, i, kt + 1); }
        }
        REPC(2, cur);
        __syncthreads();
    }
#undef REPC
#undef SA
#undef SB

    // Epilogue: per-fragment Q/K/V routing over 3 reps x 4 ft (16-wide fragments;
    // matrix boundaries are multiples of 16).
#pragma unroll
    for (int rp = 0; rp < 3; ++rp) {
#pragma unroll
    for (int ft = 0; ft < 4; ++ft) {
        const int featg = blockIdx.y * 384 + rp * 128 + wn + ft * 16 + quad * 4;
        const int mat = featg >> 10;           // 0=Q, 1=K, 2=V
        const int fin = featg & 1023;
        if (mat < 2) {
            // Q/K: [b,h,s,d]; lane owns 4 consecutive d -> 8B stores. Q gets QSCALE.
            const float* bp = (mat == 0) ? bq : bk;
            unsigned short* op = (mat == 0) ? Qo : Ko;
            const float sc = (mat == 0) ? QSCALE : 1.0f;
            const float4 b4 = *(const float4*)(bp + fin);
            const int h = fin >> 6, d = fin & 63;
#pragma unroll
            for (int st = 0; st < 4; ++st) {
                const int sg = blockIdx.x * 128 + wm + st * 16 + l16;
                const int b = sg >> 10, s = sg & 1023;
                ushortx4 o4;
                o4[0] = f2bf((acc[rp][ft][st][0] + b4.x) * sc);
                o4[1] = f2bf((acc[rp][ft][st][1] + b4.y) * sc);
                o4[2] = f2bf((acc[rp][ft][st][2] + b4.z) * sc);
                o4[3] = f2bf((acc[rp][ft][st][3] + b4.w) * sc);
                *(ushortx4*)(op + (((size_t)(b * 16 + h) * 1024 + s) * 64 + d)) = o4;
            }
        } else {
            // V: [b,h,d,s'] with per-64-window PV-fragment permutation:
            // s = 64a + st*16 + q*4 + j -> s' = 64a + (st>>1)*32 + q*8 + (st&1)*4 + j
            const float4 b4 = *(const float4*)(bv + fin);
#pragma unroll
            for (int r = 0; r < 4; ++r) {
                const int fr = fin + r;
                const int h = fr >> 6, d = fr & 63;
                const float bias = (r == 0) ? b4.x : (r == 1) ? b4.y : (r == 2) ? b4.z : b4.w;
#pragma unroll
                for (int st = 0; st < 4; ++st) {
                    const int sg = blockIdx.x * 128 + wm + st * 16 + l16;
                    const int b = sg >> 10, s = sg & 1023;
                    const int sp = (s & ~63) + (st >> 1) * 32 + (l16 >> 2) * 8 +
                                   (st & 1) * 4 + (l16 & 3);
                    Vo[((size_t)(b * 16 + h) * 64 + d) * 1024 + sp] = f2bf(acc[rp][ft][st][r] + bias);
                }
            }
        }
    }
    }
}

// ---------------- flash attention: 128-row Q tile, dbuf KVBLK=64, 1 barrier/kt ------
// grid (128, 8): x = head, y = 128-row q-tile. r14: double-buffered K/V staging —
// stage kt+1 at iteration top, compute kt, ONE __syncthreads per kt (its vmcnt
// drain lands a prefetch that flew under the whole compute). r13's sync-stage-sync
// exposed the stage latency 8x (~1.2 us each); this exposes ~0.
// LDS 36 KB -> 4 blocks/CU, 1024 blocks = 1 balanced round.
// Softmax: mask folded into QK^T C-init; P row-sum via ones-MFMA; P pack via
// shift-truncate; exp via raw v_exp_f32 (r12).
__global__ __launch_bounds__(256) void attn(
    const unsigned short* __restrict__ Q,   // [b,h,s,d] (scaled by 0.125*log2e)
    const unsigned short* __restrict__ Kg,  // [b,h,s,d]
    const unsigned short* __restrict__ Vt,  // [b,h,d,s'] (permuted)
    const float* __restrict__ mask,         // [B][S]
    unsigned short* __restrict__ ctx)       // [B,S,H] bf16
{
    __shared__ unsigned short Ks[2][4096];   // [buf][64 k-rows x 64 d]
    __shared__ unsigned short Vs[2][4096];   // [buf][64 d-rows x 64 k]
    __shared__ float Msall[1024];

    const int t = threadIdx.x;
    const int wave = t >> 6, lane = t & 63, quad = lane >> 4, l16 = lane & 15;
    const int s7 = l16 & 7;
    const int head = blockIdx.x;
    const int b = head >> 4, h = head & 15;
    const int q0 = blockIdx.y * 128;
    const unsigned short* Qh = Q + (size_t)head * 65536;
    const unsigned short* Kh = Kg + (size_t)head * 65536;
    const unsigned short* Vh = Vt + (size_t)head * 65536;

    const int srow = t >> 3;
    const int scol = ((t & 7) ^ (srow & 7)) * 8;

#define SKV(bf_, kt_)                                                               \
    do {                                                                            \
        _Pragma("unroll")                                                           \
        for (int i_ = 0; i_ < 2; i_++) {                                            \
            ASYNC16(Kh + (size_t)((kt_) * 64 + i_ * 32 + srow) * 64 + scol,         \
                    &Ks[bf_][i_ * 2048 + t * 8]);                                   \
            ASYNC16(Vh + (size_t)(i_ * 32 + srow) * 1024 + (kt_) * 64 + scol,       \
                    &Vs[bf_][i_ * 2048 + t * 8]);                                   \
        }                                                                           \
    } while (0)

    {   // mask row -> LDS, pre-scaled by log2e
        float4 m4 = *(const float4*)(mask + b * 1024 + t * 4);
        m4.x *= LOG2E; m4.y *= LOG2E; m4.z *= LOG2E; m4.w *= LOG2E;
        *(float4*)(Msall + t * 4) = m4;
    }

    // Q fragments direct from global: qf[qg][s][j] = Q[q0+wave*32+qg*16+l16][s*32+quad*8+j]
    bf16x8 qf[2][2];
#pragma unroll
    for (int qg = 0; qg < 2; qg++) {
        const unsigned short* qp = Qh + (size_t)(q0 + wave * 32 + qg * 16 + l16) * 64 + quad * 8;
        qf[qg][0] = *(const bf16x8*)(qp);
        qf[qg][1] = *(const bf16x8*)(qp + 32);
    }

    const short4v ones = {(short)0x3F80, (short)0x3F80, (short)0x3F80, (short)0x3F80};
    floatx4 sum_acc[2] = {};    // all rows identical = full P row-sum per q-col l16
    floatx4 o_acc[2][4] = {};   // [qg][dt]: O^T rows d = dt*16+quad*4+r, col q = l16

    // prologue: stage tile 0; barrier also covers the Msall writes.
    SKV(0, 0);
    __syncthreads();

#pragma unroll 1
    for (int kt = 0; kt < 16; ++kt) {
        const int cur = kt & 1, nb = cur ^ 1;
        if (kt < 15) SKV(nb, kt + 1);

        const unsigned short* Ksj = Ks[cur];
        const unsigned short* Vsj = Vs[cur];
        const int kbase = kt * 64;

        short4v pf0[4], pf1[4];
#pragma unroll
        for (int nt = 0; nt < 4; nt++) {
            int krow = nt * 16 + l16;
            bf16x8 kf0 = *(const bf16x8*)(Ksj + krow * 64 + ((quad ^ s7) * 8));
            bf16x8 kf1 = *(const bf16x8*)(Ksj + krow * 64 + (((4 + quad) ^ s7) * 8));
            floatx4 mk = *(const floatx4*)(Msall + kbase + nt * 16 + quad * 4);
            floatx4 z0 = mk;   // mask folded into accumulator init
            z0 = mfma32(kf0, qf[0][0], z0);
            z0 = mfma32(kf1, qf[0][1], z0);
            floatx4 z1 = mk;
            z1 = mfma32(kf0, qf[1][0], z1);
            z1 = mfma32(kf1, qf[1][1], z1);
#pragma unroll
            for (int r = 0; r < 4; r++) {
                pf0[nt][r] = (short)(__float_as_uint(fast_exp2(z0[r])) >> 16);
                pf1[nt][r] = (short)(__float_as_uint(fast_exp2(z1[r])) >> 16);
            }
            sum_acc[0] = mfma16(ones, pf0[nt], sum_acc[0]);
            sum_acc[1] = mfma16(ones, pf1[nt], sum_acc[1]);
        }

        // O^T += V^T P^T; Vs permuted so (nt,nt+1) fragments are one b128 read.
#pragma unroll
        for (int dt = 0; dt < 4; dt++) {
            int vrow = dt * 16 + l16;
            ushortx8 v01 = *(const ushortx8*)(Vsj + vrow * 64 + ((quad ^ s7) * 8));
            ushortx8 v23 = *(const ushortx8*)(Vsj + vrow * 64 + (((4 + quad) ^ s7) * 8));
            short4v vf0 = {(short)v01[0], (short)v01[1], (short)v01[2], (short)v01[3]};
            short4v vf1 = {(short)v01[4], (short)v01[5], (short)v01[6], (short)v01[7]};
            short4v vf2 = {(short)v23[0], (short)v23[1], (short)v23[2], (short)v23[3]};
            short4v vf3 = {(short)v23[4], (short)v23[5], (short)v23[6], (short)v23[7]};
            o_acc[0][dt] = mfma16(vf0, pf0[0], o_acc[0][dt]);
            o_acc[0][dt] = mfma16(vf1, pf0[1], o_acc[0][dt]);
            o_acc[0][dt] = mfma16(vf2, pf0[2], o_acc[0][dt]);
            o_acc[0][dt] = mfma16(vf3, pf0[3], o_acc[0][dt]);
            o_acc[1][dt] = mfma16(vf0, pf1[0], o_acc[1][dt]);
            o_acc[1][dt] = mfma16(vf1, pf1[1], o_acc[1][dt]);
            o_acc[1][dt] = mfma16(vf2, pf1[2], o_acc[1][dt]);
            o_acc[1][dt] = mfma16(vf3, pf1[3], o_acc[1][dt]);
        }
        __syncthreads();
    }
#undef SKV

#pragma unroll
    for (int qg = 0; qg < 2; qg++) {
        float inv_l = 1.0f / sum_acc[qg][0];
        int qrow = q0 + wave * 32 + qg * 16 + l16;
#pragma unroll
        for (int dt = 0; dt < 4; dt++) {
            ushortx4 o4;
#pragma unroll
            for (int r = 0; r < 4; r++) o4[r] = f2bf(o_acc[qg][dt][r] * inv_l);
            *(ushortx4*)(ctx + ((size_t)(b * 1024 + qrow)) * 1024 + h * 64 + dt * 16 + quad * 4) = o4;
        }
    }
}

// ---------------- out-proj GEMM + bias + bf16 residual -> x (bf16) ----------------
__global__ __launch_bounds__(256) void gemm_proj(
    const unsigned short* __restrict__ A,   // ctx bf16 [8192][1024]
    const unsigned short* __restrict__ W,   // Wo bf16 [1024][1024]
    const float* __restrict__ bo,
    const unsigned short* __restrict__ resid,  // hid_bf [8192][1024]
    unsigned short* __restrict__ X)         // bf16 [8192][1024]
{
    __shared__ unsigned short As[2][8192];
    __shared__ unsigned short Bs[2][8192];
    const int t = threadIdx.x;
    const int wave = t >> 6, lane = t & 63;
    const int quad = lane >> 4, l16 = lane & 15;
    const int wm = (wave >> 1) * 64, wn = (wave & 1) * 64;
    const int srow = t >> 3;
    const int scol = ((t & 7) ^ (srow & 7)) * 8;

    const unsigned short* Ag = A + ((size_t)blockIdx.x * 128 + srow) * 1024 + scol;
    const unsigned short* Wg = W + ((size_t)blockIdx.y * 128 + srow) * 1024 + scol;

    floatx4 acc[4][4] = {};
    kloop_dbuf<false>(Ag, Wg, As, Bs, wm, wn, l16, quad, t, acc);

#pragma unroll
    for (int nt = 0; nt < 4; nt++) {
        int gn = blockIdx.y * 128 + wn + nt * 16 + l16;
        float bias = bo[gn];
#pragma unroll
        for (int mt = 0; mt < 4; mt++) {
#pragma unroll
            for (int r = 0; r < 4; r++) {
                int gm = blockIdx.x * 128 + wm + mt * 16 + quad * 4 + r;
                size_t off = (size_t)gm * 1024 + gn;
                X[off] = f2bf(acc[mt][nt][r] + bias + bf2f(resid[off]));
            }
        }
    }
}

// ---------------- LayerNorm: one WAVE per token row (r14) ---------------------------
// 4 rows/block, 2048 blocks. 16 elems/lane (32B coalesced). Pure shfl_xor reduce —
// no LDS, no barriers (the old 4-elem/thread block-reduce version paid 2 barriers +
// an LDS round-trip per tiny 2KB row).
__global__ __launch_bounds__(256) void ln_k(const unsigned short* __restrict__ X,
                                            const float* __restrict__ g,
                                            const float* __restrict__ be,
                                            float* __restrict__ out)
{
    const int wave = threadIdx.x >> 6, lane = threadIdx.x & 63;
    const int row = blockIdx.x * 4 + wave;
    const unsigned short* xr = X + (size_t)row * 1024 + lane * 16;
    ushortx8 xa = *(const ushortx8*)(xr);
    ushortx8 xb = *(const ushortx8*)(xr + 8);
    float v[16];
#pragma unroll
    for (int i = 0; i < 8; i++) { v[i] = bf2f(xa[i]); v[8 + i] = bf2f(xb[i]); }
    float s = 0.f, ss = 0.f;
#pragma unroll
    for (int i = 0; i < 16; i++) { s += v[i]; ss += v[i] * v[i]; }
#pragma unroll
    for (int off = 1; off < 64; off <<= 1) {
        s += __shfl_xor(s, off);
        ss += __shfl_xor(ss, off);
    }
    float mu = s * (1.f / 1024.f);
    float var = ss * (1.f / 1024.f) - mu * mu;
    float inv = rsqrtf(var + 1e-12f);
    const float4* gp = (const float4*)(g + lane * 16);
    const float4* bp = (const float4*)(be + lane * 16);
    float* op = out + (size_t)row * 1024 + lane * 16;
#pragma unroll
    for (int q = 0; q < 4; q++) {
        float4 gv = gp[q], bv = bp[q];
        float4 o;
        o.x = (v[q * 4 + 0] - mu) * inv * gv.x + bv.x;
        o.y = (v[q * 4 + 1] - mu) * inv * gv.y + bv.y;
        o.z = (v[q * 4 + 2] - mu) * inv * gv.z + bv.z;
        o.w = (v[q * 4 + 3] - mu) * inv * gv.w + bv.w;
        *(float4*)(op + q * 4) = o;
    }
}

extern "C" void kernel_launch(void* const* d_in, const int* in_sizes, int n_in,
                              void* d_out, int out_size, void* d_ws, size_t ws_size,
                              hipStream_t stream)
{
    const float* hidden = (const float*)d_in[0];
    const float* mask   = (const float*)d_in[1];
    const float* Wq = (const float*)d_in[2];
    const float* bq = (const float*)d_in[3];
    const float* Wk = (const float*)d_in[4];
    const float* bk = (const float*)d_in[5];
    const float* Wv = (const float*)d_in[6];
    const float* bv = (const float*)d_in[7];
    const float* Wo = (const float*)d_in[8];
    const float* bo = (const float*)d_in[9];
    const float* gamma = (const float*)d_in[10];
    const float* beta  = (const float*)d_in[11];
    float* out = (float*)d_out;

    char* ws = (char*)d_ws;
    // layout (bytes): hid_bf 16M | wqkv_bf 6M | wo_bf 2M | vt_bf 16M | ctx_bf 16M | q_bf 16M | k_bf 16M
    // x (bf16, 16M) aliases q_bf (dead after attn). total 88M.
    unsigned short* hid_bf  = (unsigned short*)(ws + 0);
    unsigned short* wqkv_bf = (unsigned short*)(ws + 16777216);
    unsigned short* wo_bf   = (unsigned short*)(ws + 23068672);
    unsigned short* vt_bf   = (unsigned short*)(ws + 25165824);
    unsigned short* ctx_bf  = (unsigned short*)(ws + 41943040);
    unsigned short* q_bf    = (unsigned short*)(ws + 58720256);
    unsigned short* k_bf    = (unsigned short*)(ws + 75497472);
    unsigned short* x_bf    = (unsigned short*)(ws + 58720256);

    cvt_all<<<6144, 256, 0, stream>>>(hidden, Wq, Wk, Wv, Wo, hid_bf, wqkv_bf, wo_bf);

    gemm_qkv<<<dim3(64, 8), 256, 0, stream>>>(hid_bf, wqkv_bf, bq, bk, bv, q_bf, k_bf, vt_bf);
    attn<<<dim3(128, 8), 256, 0, stream>>>(q_bf, k_bf, vt_bf, mask, ctx_bf);
    gemm_proj<<<dim3(64, 8), 256, 0, stream>>>(ctx_bf, wo_bf, bo, hid_bf, x_bf);
    ln_k<<<2048, 256, 0, stream>>>(x_bf, gamma, beta, out);
}